// Round 7
// baseline (68.226 us; speedup 1.0000x reference)
//
#include <hip/hip_runtime.h>
#include <hip/hip_bf16.h>

// Problem constants (fixed by reference)
#define NB   32      // N  (batch)
#define CIN  32      // INC
#define COUT 32      // OUTC
#define INN_ 16384   // INN
#define ON   4096    // OUTN
#define MD   16      // MAXD

// ---------------------------------------------------------------------------
// Kernel 1: premix + transpose, bf16 output. NO LDS in the main loop.
//   zT[n][j][c] = sum_i weight[i][c] * x[n][i][j]   (stored as bf16 pairs)
// Wave w owns c-slice [8w,8w+8) (base in SGPR via readfirstlane -> weight
// reads are s_load on the scalar pipe, 8 per i). Lane owns 8 consecutive j:
// 2x float4 global loads per i, coalesced, 2-i software lookahead.
// acc[8][8] = 64 VGPR; ~112 total < 128 cap (launch_bounds(256,4)).
// Grid: (INN/512, N), block 256 (j-tile 512).
// ---------------------------------------------------------------------------
__global__ __launch_bounds__(256, 4) void premix_kernel(
    const float* __restrict__ x,
    const float* __restrict__ weight,
    unsigned* __restrict__ zT) {  // bf16x2 words, layout [n][j][c/2]
  const int lane = threadIdx.x & 63;
  const int wv   = threadIdx.x >> 6;  // 0..3
  const int cw   = __builtin_amdgcn_readfirstlane(wv << 3);  // SGPR c-base
  const int n    = blockIdx.y;
  const int j0   = blockIdx.x * 512 + lane * 8;

  // float4 view of x[n]; i-row stride = 16384/4 = 4096 float4.
  const float4* xp4 =
      (const float4*)(x + (((size_t)n * CIN) << 14)) + (j0 >> 2);

  float acc[8][8];
#pragma unroll
  for (int jj = 0; jj < 8; ++jj)
#pragma unroll
    for (int c = 0; c < 8; ++c) acc[jj][c] = 0.f;

#define STEP(I, B0, B1)                                              \
  {                                                                  \
    _Pragma("unroll") for (int c = 0; c < 8; ++c) {                  \
      const float wvv = weight[(I)*COUT + cw + c]; /* s_load */      \
      acc[0][c] += (B0).x * wvv;                                     \
      acc[1][c] += (B0).y * wvv;                                     \
      acc[2][c] += (B0).z * wvv;                                     \
      acc[3][c] += (B0).w * wvv;                                     \
      acc[4][c] += (B1).x * wvv;                                     \
      acc[5][c] += (B1).y * wvv;                                     \
      acc[6][c] += (B1).z * wvv;                                     \
      acc[7][c] += (B1).w * wvv;                                     \
    }                                                                \
  }

  float4 pA0 = xp4[0], pA1 = xp4[1];
  float4 pB0 = xp4[4096], pB1 = xp4[4097];
#pragma unroll
  for (int i = 0; i < CIN; i += 2) {
    float4 nA0, nA1, nB0, nB1;
    if (i + 2 < CIN) {
      nA0 = xp4[(size_t)(i + 2) * 4096];
      nA1 = xp4[(size_t)(i + 2) * 4096 + 1];
      nB0 = xp4[(size_t)(i + 3) * 4096];
      nB1 = xp4[(size_t)(i + 3) * 4096 + 1];
    }
    STEP(i, pA0, pA1)
    STEP(i + 1, pB0, pB1)
    pA0 = nA0; pA1 = nA1; pB0 = nB0; pB1 = nB1;
  }
#undef STEP

  // Store: 8 j-rows, 16 B (8 c = 4 bf16x2 words) each at this wave's quarter.
  unsigned* base = zT + ((size_t)((n << 14) + j0) << 4) + (cw >> 1);
#pragma unroll
  for (int jj = 0; jj < 8; ++jj) {
    unsigned pk[4];
#pragma unroll
    for (int q = 0; q < 4; ++q) {
      __hip_bfloat162 h = __float22bfloat162_rn(
          make_float2(acc[jj][2 * q], acc[jj][2 * q + 1]));
      pk[q] = *(unsigned*)&h;
    }
    *(uint4*)(base + jj * 16) = *(uint4*)pk;
  }
}

// ---------------------------------------------------------------------------
// Kernel 2: gather-pool + bias from bf16 zT.
//   out[n][c][o] = bias[c][o] + sum_{m<deg[o]} zT[n][A[o][m]][c]
// 16 lanes per o (each lane: one bf16x2 word = 2 channels); 4 o-streams per
// thread with fp32 register accumulators. A + degrees staged in LDS.
// Grid: 2048 blocks (XCD-swizzled), block 256. Each block: one n, 64 o.
// ---------------------------------------------------------------------------
__global__ __launch_bounds__(256) void gather_pool_kernel(
    const unsigned* __restrict__ zT,  // bf16x2 words, [n][j][c/2]
    const int* __restrict__ A,
    const float* __restrict__ mask,
    const float* __restrict__ bias,
    float* __restrict__ out) {
  __shared__ int   aIdx[64 * MD];    // 4 KB
  __shared__ int   degS[64];
  __shared__ float otile[COUT][65];  // (c+o)%32 banks: conflict-free

  // XCD-aware swizzle: block L -> XCD L%8; each XCD owns 4 consecutive n,
  // so zT[n] (1 MB bf16) stays L2-resident per XCD.
  const int L    = blockIdx.x;
  const int xcd  = L & 7;
  const int slot = L >> 3;                 // 0..255
  const int n    = xcd * 4 + (slot >> 6);  // 4 n per xcd
  const int o0   = (slot & 63) * 64;

  const int tid = threadIdx.x;

  // Stage A rows: 1024 ints, one int4 per thread, coalesced.
  ((int4*)aIdx)[tid] = ((const int4*)(A + o0 * MD))[tid];

  // Degrees: mask rows are exactly {1.0 x deg, 0.0 ...}.
  if (tid < 64) {
    const float4* mrow = (const float4*)(mask + (size_t)(o0 + tid) * MD);
    float s = 0.f;
#pragma unroll
    for (int q = 0; q < 4; ++q) {
      float4 v = mrow[q];
      s += v.x + v.y + v.z + v.w;
    }
    degS[tid] = (int)(s + 0.5f);
  }
  __syncthreads();

  const int l16 = tid & 15;  // channel pair index
  const int grp = tid >> 4;  // 0..15: group handles o = o0 + grp*4 + k

  const unsigned* zn = zT + (((size_t)n) << 18);  // zT[n]: 16384*16 words

  float2 acc[4];
  int    deg[4];
#pragma unroll
  for (int k = 0; k < 4; ++k) {
    acc[k] = make_float2(0.f, 0.f);
    deg[k] = degS[grp * 4 + k];
  }

#pragma unroll
  for (int m = 0; m < MD; ++m) {
#pragma unroll
    for (int k = 0; k < 4; ++k) {
      if (m < deg[k]) {  // uniform within 16-lane group
        const int idx = aIdx[(grp * 4 + k) * MD + m];
        const unsigned w = zn[idx * 16 + l16];  // 64B per group, coalesced
        acc[k].x += __uint_as_float(w << 16);
        acc[k].y += __uint_as_float(w & 0xffff0000u);
      }
    }
  }

#pragma unroll
  for (int k = 0; k < 4; ++k) {
    const int o = grp * 4 + k;
    otile[2 * l16][o]     = acc[k].x;
    otile[2 * l16 + 1][o] = acc[k].y;
  }
  __syncthreads();

  // Coalesced write + bias: lanes over o.
  const int ol = tid & 63;
  const int cg = (tid >> 6) * 8;
#pragma unroll
  for (int jj = 0; jj < 8; ++jj) {
    const int cc = cg + jj;
    out[((size_t)(n * COUT + cc)) * ON + o0 + ol] =
        otile[cc][ol] + bias[cc * ON + o0 + ol];
  }
}

// ---------------------------------------------------------------------------
// Fallback (ws too small): pool directly from x (strided gather), then mix.
// ---------------------------------------------------------------------------
__global__ __launch_bounds__(256) void fused_direct_kernel(
    const float* __restrict__ x,
    const int* __restrict__ A,
    const float* __restrict__ mask,
    const float* __restrict__ weight,
    const float* __restrict__ bias,
    float* __restrict__ out) {
  __shared__ float pooled[64][33];
  __shared__ float wl[CIN * COUT];

  const int n  = blockIdx.y;
  const int o0 = blockIdx.x * 64;
  const int tid = threadIdx.x;

  for (int k = tid; k < CIN * COUT; k += 256) wl[k] = weight[k];

  const int c = tid & 31;
  const int g = tid >> 5;
  for (int oo = g; oo < 64; oo += 8) {
    const int o = o0 + oo;
    float acc = 0.f;
#pragma unroll
    for (int m = 0; m < MD; ++m) {
      const float f = mask[o * MD + m];
      if (f == 0.f) break;
      const int idx = A[o * MD + m];
      acc += f * x[(((size_t)(n * CIN + c)) << 14) + idx];
    }
    pooled[oo][c] = acc;
  }
  __syncthreads();

  const int ol = tid & 63;
  const int cg = (tid >> 6) * 8;
  float y[8];
#pragma unroll
  for (int jj = 0; jj < 8; ++jj) y[jj] = bias[(cg + jj) * ON + o0 + ol];
  for (int i = 0; i < CIN; ++i) {
    const float p = pooled[ol][i];
#pragma unroll
    for (int jj = 0; jj < 8; ++jj) y[jj] += p * wl[i * 32 + cg + jj];
  }
#pragma unroll
  for (int jj = 0; jj < 8; ++jj)
    out[((size_t)(n * COUT + cg + jj)) * ON + o0 + ol] = y[jj];
}

extern "C" void kernel_launch(void* const* d_in, const int* in_sizes, int n_in,
                              void* d_out, int out_size, void* d_ws, size_t ws_size,
                              hipStream_t stream) {
  const float* x      = (const float*)d_in[0];
  const int*   A      = (const int*)d_in[1];
  const float* mask   = (const float*)d_in[2];
  const float* weight = (const float*)d_in[3];
  const float* bias   = (const float*)d_in[4];
  float* out = (float*)d_out;

  const size_t need = (size_t)NB * INN_ * COUT * sizeof(unsigned short);  // 32MB
  if (ws_size >= need) {
    unsigned* zT = (unsigned*)d_ws;
    premix_kernel<<<dim3(INN_ / 512, NB), 256, 0, stream>>>(x, weight, zT);
    gather_pool_kernel<<<2048, 256, 0, stream>>>(zT, A, mask, bias, out);
  } else {
    fused_direct_kernel<<<dim3(ON / 64, NB), 256, 0, stream>>>(
        x, A, mask, weight, bias, out);
  }
}

// Round 8
// 45.865 us; speedup vs baseline: 1.4876x; 1.4876x over previous
//
#include <hip/hip_runtime.h>
#include <hip/hip_bf16.h>

// Problem constants (fixed by reference)
#define NB   32      // N  (batch)
#define CIN  32      // INC
#define COUT 32      // OUTC
#define INN_ 16384   // INN
#define ON   4096    // OUTN
#define MD   16      // MAXD

typedef __attribute__((ext_vector_type(8))) short bf16x8;  // 8 bf16 = 4 VGPR
typedef __attribute__((ext_vector_type(4))) float f32x4;

// ---------------------------------------------------------------------------
// Kernel 1: premix via MFMA.  zT[n][j][c] = sum_i x[n][i][j] * w[i][c], bf16.
// Per 16-j subtile: A-frag = x^T (lane l: x[i=(l>>4)*8+q][j0+(l&15)], 8
// coalesced global dwords), B-frags = w (loop-invariant, hi/lo bf16 split).
// 3-term split (xh*wh + xh*wl + xl*wh) keeps error at plain-bf16-zT level.
// D-frags -> per-wave XOR-swizzled LDS otile (all DS ops <=2-way) -> 1KB
// coalesced stores. One wave owns a 64-j strip; 4 strips/wave.
// Grid: 512 blocks x 256 thr (4 waves), 2 blocks/CU.
// ---------------------------------------------------------------------------
__global__ __launch_bounds__(256, 2) void premix_mfma_kernel(
    const float* __restrict__ x,
    const float* __restrict__ weight,
    unsigned short* __restrict__ zT) {  // bf16, layout [n][j][c]
  __shared__ unsigned short ot[4][64 * 40];  // per-wave otile, pitch 40 halves

  const int tid  = threadIdx.x;
  const int lane = tid & 63;
  const int wv   = tid >> 6;
  const int l15  = lane & 15;
  const int kq0  = (lane >> 4) << 3;  // i-base for this lane's k-slice
  unsigned short* otw = ot[wv];

  // ---- B fragments (loop-invariant): w hi/lo for c0=0 and c0=16.
  bf16x8 whA, whB, wlA, wlB;
#pragma unroll
  for (int q = 0; q < 8; ++q) {
    const float wA = weight[(kq0 + q) * COUT + l15];
    const float wB = weight[(kq0 + q) * COUT + 16 + l15];
    const unsigned uA = __float_as_uint(wA), uB = __float_as_uint(wB);
    const float hA = __uint_as_float(uA & 0xffff0000u);
    const float hB = __uint_as_float(uB & 0xffff0000u);
    whA[q] = (short)(uA >> 16);
    whB[q] = (short)(uB >> 16);
    wlA[q] = (short)(__float_as_uint(wA - hA) >> 16);
    wlB[q] = (short)(__float_as_uint(wB - hB) >> 16);
  }

  // 8192 strips of 64 j; wave gw handles strips gw*4 .. gw*4+3.
  const int gw = blockIdx.x * 4 + wv;
  for (int t = 0; t < 4; ++t) {
    const int s  = gw * 4 + t;       // strip id
    const int n  = s >> 8;
    const int j0 = (s & 255) << 6;
    const float* xb = x + (((size_t)(n * CIN + kq0)) << 14) + j0 + l15;

#pragma unroll
    for (int sub = 0; sub < 4; ++sub) {
      // 8 independent coalesced loads (each instr: 4 rows x 64B lines).
      float xv[8];
#pragma unroll
      for (int q = 0; q < 8; ++q)
        xv[q] = xb[((size_t)q << 14) + (sub << 4)];

      bf16x8 xh, xl;
#pragma unroll
      for (int q = 0; q < 8; ++q) {
        const unsigned u = __float_as_uint(xv[q]);
        const float hi = __uint_as_float(u & 0xffff0000u);
        xh[q] = (short)(u >> 16);
        xl[q] = (short)(__float_as_uint(xv[q] - hi) >> 16);
      }

      f32x4 d0 = {0.f, 0.f, 0.f, 0.f}, d1 = {0.f, 0.f, 0.f, 0.f};
      d0 = __builtin_amdgcn_mfma_f32_16x16x32_bf16(xh, whA, d0, 0, 0, 0);
      d0 = __builtin_amdgcn_mfma_f32_16x16x32_bf16(xh, wlA, d0, 0, 0, 0);
      d0 = __builtin_amdgcn_mfma_f32_16x16x32_bf16(xl, whA, d0, 0, 0, 0);
      d1 = __builtin_amdgcn_mfma_f32_16x16x32_bf16(xh, whB, d1, 0, 0, 0);
      d1 = __builtin_amdgcn_mfma_f32_16x16x32_bf16(xh, wlB, d1, 0, 0, 0);
      d1 = __builtin_amdgcn_mfma_f32_16x16x32_bf16(xl, whB, d1, 0, 0, 0);

      // D -> otile (bf16 round-half-up), XOR-swizzled: banks fully disjoint.
#pragma unroll
      for (int r = 0; r < 4; ++r) {
        const int row = (sub << 4) + ((lane >> 4) << 2) + r;  // j within strip
        const int swz = ((row >> 2) & 3) << 3;
        otw[row * 40 + (l15 ^ swz)] =
            (unsigned short)((__float_as_uint(d0[r]) + 0x8000u) >> 16);
        otw[row * 40 + ((16 + l15) ^ swz)] =
            (unsigned short)((__float_as_uint(d1[r]) + 0x8000u) >> 16);
      }
    }

    // Read out (<=2-way banks) and store coalesced: 1 KB per pass.
    uint4* zrow = (uint4*)(zT + (((size_t)(n << 14) + j0) << 5));
#pragma unroll
    for (int p = 0; p < 4; ++p) {
      const int row = (p << 4) + (lane >> 2);
      const int ch  = lane & 3;
      const int swz = ((row >> 2) & 3) << 3;
      const uint4 v = *(const uint4*)(otw + row * 40 + ((ch << 3) ^ swz));
      zrow[row * 4 + ch] = v;  // lanes cover 1 KB contiguous
    }
  }
}

// ---------------------------------------------------------------------------
// Kernel 2: gather-pool + bias from bf16 zT (unchanged from R6).
//   out[n][c][o] = bias[c][o] + sum_{m<deg[o]} zT[n][A[o][m]][c]
// ---------------------------------------------------------------------------
__global__ __launch_bounds__(256) void gather_pool_kernel(
    const unsigned* __restrict__ zT,  // bf16x2 words, [n][j][c/2]
    const int* __restrict__ A,
    const float* __restrict__ mask,
    const float* __restrict__ bias,
    float* __restrict__ out) {
  __shared__ int   aIdx[64 * MD];    // 4 KB
  __shared__ int   degS[64];
  __shared__ float otile[COUT][65];  // (c+o)%32 banks: conflict-free

  const int L    = blockIdx.x;
  const int xcd  = L & 7;
  const int slot = L >> 3;
  const int n    = xcd * 4 + (slot >> 6);
  const int o0   = (slot & 63) * 64;

  const int tid = threadIdx.x;

  ((int4*)aIdx)[tid] = ((const int4*)(A + o0 * MD))[tid];

  if (tid < 64) {
    const float4* mrow = (const float4*)(mask + (size_t)(o0 + tid) * MD);
    float s = 0.f;
#pragma unroll
    for (int q = 0; q < 4; ++q) {
      float4 v = mrow[q];
      s += v.x + v.y + v.z + v.w;
    }
    degS[tid] = (int)(s + 0.5f);
  }
  __syncthreads();

  const int l16 = tid & 15;
  const int grp = tid >> 4;

  const unsigned* zn = zT + (((size_t)n) << 18);

  float2 acc[4];
  int    deg[4];
#pragma unroll
  for (int k = 0; k < 4; ++k) {
    acc[k] = make_float2(0.f, 0.f);
    deg[k] = degS[grp * 4 + k];
  }

#pragma unroll
  for (int m = 0; m < MD; ++m) {
#pragma unroll
    for (int k = 0; k < 4; ++k) {
      if (m < deg[k]) {
        const int idx = aIdx[(grp * 4 + k) * MD + m];
        const unsigned w = zn[idx * 16 + l16];
        acc[k].x += __uint_as_float(w << 16);
        acc[k].y += __uint_as_float(w & 0xffff0000u);
      }
    }
  }

#pragma unroll
  for (int k = 0; k < 4; ++k) {
    const int o = grp * 4 + k;
    otile[2 * l16][o]     = acc[k].x;
    otile[2 * l16 + 1][o] = acc[k].y;
  }
  __syncthreads();

  const int ol = tid & 63;
  const int cg = (tid >> 6) * 8;
#pragma unroll
  for (int jj = 0; jj < 8; ++jj) {
    const int cc = cg + jj;
    out[((size_t)(n * COUT + cc)) * ON + o0 + ol] =
        otile[cc][ol] + bias[cc * ON + o0 + ol];
  }
}

// ---------------------------------------------------------------------------
// Fallback (ws too small): pool directly from x (strided gather), then mix.
// ---------------------------------------------------------------------------
__global__ __launch_bounds__(256) void fused_direct_kernel(
    const float* __restrict__ x,
    const int* __restrict__ A,
    const float* __restrict__ mask,
    const float* __restrict__ weight,
    const float* __restrict__ bias,
    float* __restrict__ out) {
  __shared__ float pooled[64][33];
  __shared__ float wl[CIN * COUT];

  const int n  = blockIdx.y;
  const int o0 = blockIdx.x * 64;
  const int tid = threadIdx.x;

  for (int k = tid; k < CIN * COUT; k += 256) wl[k] = weight[k];

  const int c = tid & 31;
  const int g = tid >> 5;
  for (int oo = g; oo < 64; oo += 8) {
    const int o = o0 + oo;
    float acc = 0.f;
#pragma unroll
    for (int m = 0; m < MD; ++m) {
      const float f = mask[o * MD + m];
      if (f == 0.f) break;
      const int idx = A[o * MD + m];
      acc += f * x[(((size_t)(n * CIN + c)) << 14) + idx];
    }
    pooled[oo][c] = acc;
  }
  __syncthreads();

  const int ol = tid & 63;
  const int cg = (tid >> 6) * 8;
  float y[8];
#pragma unroll
  for (int jj = 0; jj < 8; ++jj) y[jj] = bias[(cg + jj) * ON + o0 + ol];
  for (int i = 0; i < CIN; ++i) {
    const float p = pooled[ol][i];
#pragma unroll
    for (int jj = 0; jj < 8; ++jj) y[jj] += p * wl[i * 32 + cg + jj];
  }
#pragma unroll
  for (int jj = 0; jj < 8; ++jj)
    out[((size_t)(n * COUT + cg + jj)) * ON + o0 + ol] = y[jj];
}

extern "C" void kernel_launch(void* const* d_in, const int* in_sizes, int n_in,
                              void* d_out, int out_size, void* d_ws, size_t ws_size,
                              hipStream_t stream) {
  const float* x      = (const float*)d_in[0];
  const int*   A      = (const int*)d_in[1];
  const float* mask   = (const float*)d_in[2];
  const float* weight = (const float*)d_in[3];
  const float* bias   = (const float*)d_in[4];
  float* out = (float*)d_out;

  const size_t need = (size_t)NB * INN_ * COUT * sizeof(unsigned short);  // 32MB
  if (ws_size >= need) {
    unsigned short* zT = (unsigned short*)d_ws;
    premix_mfma_kernel<<<512, 256, 0, stream>>>(x, weight, zT);
    gather_pool_kernel<<<2048, 256, 0, stream>>>((const unsigned*)zT, A, mask,
                                                 bias, out);
  } else {
    fused_direct_kernel<<<dim3(ON / 64, NB), 256, 0, stream>>>(
        x, A, mask, weight, bias, out);
  }
}